// Round 5
// baseline (2422.200 us; speedup 1.0000x reference)
//
#include <hip/hip_runtime.h>

#define NN 50000
#define NE 1600000
#define RR 20
#define BN_EPS 1e-5f
#define SEGS (NN * RR)                    /* 1,000,000 */
#define SCAN_NB ((SEGS + 1023) / 1024)    /* 977 */

typedef __attribute__((ext_vector_type(8))) short bf16x8;
typedef __attribute__((ext_vector_type(4))) float f32x4;

__device__ __forceinline__ unsigned short f2bf(float f) {
    unsigned u = __float_as_uint(f);
    u += 0x7fff + ((u >> 16) & 1);        // RNE
    return (unsigned short)(u >> 16);
}

// ---------------- CSR build: count per (rel, dst) segment ----------------
__global__ void count_kernel(const int* __restrict__ dst, const int* __restrict__ et,
                             int* __restrict__ cnt) {
    int stride = gridDim.x * blockDim.x;
    for (int e = blockIdx.x * blockDim.x + threadIdx.x; e < NE; e += stride)
        atomicAdd(&cnt[et[e] * NN + dst[e]], 1);
}

__global__ __launch_bounds__(256) void scan1_kernel(const int* __restrict__ in,
                                                    int* __restrict__ out,
                                                    int* __restrict__ bsums, int n) {
    __shared__ int lds[256];
    int tid  = threadIdx.x;
    int base = blockIdx.x * 1024 + tid * 4;
    int v[4];
    #pragma unroll
    for (int j = 0; j < 4; ++j) v[j] = (base + j < n) ? in[base + j] : 0;
    int tsum = v[0] + v[1] + v[2] + v[3];
    lds[tid] = tsum;
    __syncthreads();
    for (int off = 1; off < 256; off <<= 1) {
        int t = (tid >= off) ? lds[tid - off] : 0;
        __syncthreads();
        lds[tid] += t;
        __syncthreads();
    }
    int run = lds[tid] - tsum;
    #pragma unroll
    for (int j = 0; j < 4; ++j) {
        if (base + j < n) out[base + j] = run;
        run += v[j];
    }
    if (tid == 255) bsums[blockIdx.x] = lds[255];
}

__global__ __launch_bounds__(1024) void scan_top_kernel(int* __restrict__ bsums, int nb) {
    __shared__ int lds[1024];
    int tid = threadIdx.x;
    int v = (tid < nb) ? bsums[tid] : 0;
    lds[tid] = v;
    __syncthreads();
    for (int off = 1; off < 1024; off <<= 1) {
        int t = (tid >= off) ? lds[tid - off] : 0;
        __syncthreads();
        lds[tid] += t;
        __syncthreads();
    }
    bsums[tid] = lds[tid] - v;
}

__global__ void scan_add_kernel(int* __restrict__ out, const int* __restrict__ bsums, int n) {
    int stride = gridDim.x * blockDim.x;
    for (int i = blockIdx.x * blockDim.x + threadIdx.x; i < n; i += stride)
        out[i] += bsums[i >> 10];
}

__global__ void set_total_kernel(int* __restrict__ offs) { offs[SEGS] = NE; }

// ------- bucket-fill: ep = {src | dl<<20, inv_cnt f32}, sorted by (rel,dst) ----------
__global__ void fill_kernel(const int* __restrict__ src, const int* __restrict__ dst,
                            const int* __restrict__ et, const int* __restrict__ offs,
                            int* __restrict__ fill, uint2* __restrict__ ep) {
    int stride = gridDim.x * blockDim.x;
    for (int e = blockIdx.x * blockDim.x + threadIdx.x; e < NE; e += stride) {
        int seg = et[e] * NN + dst[e];
        int pos = offs[seg] + atomicAdd(&fill[seg], 1);
        float ic = 1.0f / fmaxf((float)(offs[seg + 1] - offs[seg]), 1.0f);
        ep[pos] = make_uint2((unsigned)src[e] | ((unsigned)(dst[e] & 31) << 20),
                             __float_as_uint(ic));
    }
}

// ------- weight prep: Wt[l][r][n][k] bf16 (transposed), r=20 is root ---------
__global__ __launch_bounds__(256) void wprep_kernel(const float* __restrict__ Wh,
                                                    const float* __restrict__ rooth,
                                                    unsigned short* __restrict__ Wt) {
    int l = blockIdx.x / 21, r = blockIdx.x % 21;
    const float* Ws = (r < 20) ? Wh + ((size_t)l * 20 + r) * 4096
                               : rooth + (size_t)l * 4096;
    unsigned short* Wd = Wt + ((size_t)l * 21 + r) * 4096;
    int t = threadIdx.x;
    int n4 = (t & 15) * 4;
    for (int k = t >> 4; k < 64; k += 16) {
        float4 w = *(const float4*)&Ws[(size_t)k * 64 + n4];
        Wd[(n4 + 0) * 64 + k] = f2bf(w.x);
        Wd[(n4 + 1) * 64 + k] = f2bf(w.y);
        Wd[(n4 + 2) * 64 + k] = f2bf(w.z);
        Wd[(n4 + 3) * 64 + k] = f2bf(w.w);
    }
}

// ---------------- layer 0: fp32 VALU GEMM (K=84 tiny), out bf16 ----------------
__global__ __launch_bounds__(256) void rgcn_l0(
    const float* __restrict__ x, const int* __restrict__ offs,
    const uint2* __restrict__ ep,
    const float* __restrict__ W0, const float* __restrict__ root0,
    const float* __restrict__ b0, const float* __restrict__ gamma,
    const float* __restrict__ beta, const float* __restrict__ rmean,
    const float* __restrict__ rvar, unsigned short* __restrict__ outb) {
    constexpr int AP = 12;
    __shared__ float Alds[32 * AP];
    __shared__ float Wlds[4 * 64];
    const int tid = threadIdx.x;
    const int lane = tid & 63;
    const int wv = tid >> 6;
    const int og = tid & 15, nl = tid >> 4, o = og * 4;
    const int n0 = blockIdx.x * 32;
    const int nend = min(n0 + 32, NN);
    float acc0[4] = {0.f, 0.f, 0.f, 0.f}, acc1[4] = {0.f, 0.f, 0.f, 0.f};

    for (int r = 0; r <= RR; ++r) {
        __syncthreads();
        if (r < RR) {
            for (int i = tid; i < 32 * AP / 4; i += 256)
                ((float4*)Alds)[i] = make_float4(0.f, 0.f, 0.f, 0.f);
            const float* Wb = W0 + (size_t)r * 256;
            for (int i = tid; i < 64; i += 256)
                ((float4*)Wlds)[i] = ((const float4*)Wb)[i];
            __syncthreads();
            int e0 = offs[r * NN + n0], e1 = offs[r * NN + nend];
            int sl = lane >> 2, f = lane & 3;
            for (int eb = e0 + wv * 16; eb < e1; eb += 64) {
                int e = eb + sl;
                if (e < e1) {
                    uint2 p = ep[e];
                    int srcn = p.x & 0xFFFFF, dl = (p.x >> 20) & 31;
                    atomicAdd(&Alds[dl * AP + f],
                              x[(size_t)srcn * 4 + f] * __uint_as_float(p.y));
                }
            }
        } else {
            for (int i = tid; i < 128; i += 256) {
                int m = i >> 2, f2 = i & 3;
                int gn = n0 + m;
                Alds[m * AP + f2] = (gn < NN) ? x[(size_t)gn * 4 + f2] : 0.f;
            }
            for (int i = tid; i < 64; i += 256)
                ((float4*)Wlds)[i] = ((const float4*)root0)[i];
        }
        __syncthreads();
        float a0[4], a1[4];
        *(float4*)a0 = *(const float4*)&Alds[nl * AP];
        *(float4*)a1 = *(const float4*)&Alds[(nl + 16) * AP];
        #pragma unroll
        for (int j = 0; j < 4; ++j) {
            float w[4];
            *(float4*)w = *(const float4*)&Wlds[j * 64 + o];
            #pragma unroll
            for (int q = 0; q < 4; ++q) {
                acc0[q] += a0[j] * w[q];
                acc1[q] += a1[j] * w[q];
            }
        }
    }

    float bia[4], rm[4], rv[4], g[4], bt[4], sc[4];
    *(float4*)bia = *(const float4*)&b0[o];
    *(float4*)rm  = *(const float4*)&rmean[o];
    *(float4*)rv  = *(const float4*)&rvar[o];
    *(float4*)g   = *(const float4*)&gamma[o];
    *(float4*)bt  = *(const float4*)&beta[o];
    #pragma unroll
    for (int q = 0; q < 4; ++q) sc[q] = g[q] * rsqrtf(rv[q] + BN_EPS);

    int gn0 = n0 + nl, gn1 = n0 + nl + 16;
    if (gn0 < NN) {
        ushort4 pk;
        pk.x = f2bf((acc0[0] + bia[0] - rm[0]) * sc[0] + bt[0]);
        pk.y = f2bf((acc0[1] + bia[1] - rm[1]) * sc[1] + bt[1]);
        pk.z = f2bf((acc0[2] + bia[2] - rm[2]) * sc[2] + bt[2]);
        pk.w = f2bf((acc0[3] + bia[3] - rm[3]) * sc[3] + bt[3]);
        *(ushort4*)&outb[(size_t)gn0 * 64 + o] = pk;
    }
    if (gn1 < NN) {
        ushort4 pk;
        pk.x = f2bf((acc1[0] + bia[0] - rm[0]) * sc[0] + bt[0]);
        pk.y = f2bf((acc1[1] + bia[1] - rm[1]) * sc[1] + bt[1]);
        pk.z = f2bf((acc1[2] + bia[2] - rm[2]) * sc[2] + bt[2]);
        pk.w = f2bf((acc1[3] + bia[3] - rm[3]) * sc[3] + bt[3]);
        *(ushort4*)&outb[(size_t)gn1 * 64 + o] = pk;
    }
}

// ---------------- hidden layer: barrier-free edge-MFMA + LDS out-tile -----------------
// 32-node tile, 4 waves. Wave wv owns items {wv, wv+4, ...} of 21 (20 rels + root).
// Per 16-edge group: A-frags gathered straight from global h rows (lane: row=frow,
// k-chunk=kgrp), B-frags (W[n][k]) held in VGPRs per item, D rows = edges scaled by
// inv_cnt then atomicAdd'ed into LDS out[32][65]. Only 2 barriers per block.
template <bool LAST>
__global__ __launch_bounds__(256) void rgcn_hidden(
    const unsigned short* __restrict__ hin, const int* __restrict__ offs,
    const uint2* __restrict__ ep, const unsigned short* __restrict__ WtL,
    const float* __restrict__ bias, const float* __restrict__ gamma,
    const float* __restrict__ beta, const float* __restrict__ rmean,
    const float* __restrict__ rvar, unsigned short* __restrict__ outb,
    float* __restrict__ outf) {
    constexpr int ST = 65;
    __shared__ float ot[32 * ST];   // 8320 B

    const int tid  = threadIdx.x;
    const int lane = tid & 63;
    const int wv   = tid >> 6;
    const int n0   = blockIdx.x * 32;
    const int nend = min(n0 + 32, NN);
    const int frow = lane & 15;
    const int kgrp = lane >> 4;

    for (int i = tid; i < 32 * ST; i += 256) ot[i] = 0.f;
    __syncthreads();

    for (int item = wv; item < 21; item += 4) {
        // B-fragments for this item: 8 x bf16x8 = 32 VGPRs, from global (L2-hot)
        const char* Wr = (const char*)(WtL + (size_t)item * 4096);
        bf16x8 bfr[4][2];
        #pragma unroll
        for (int nb = 0; nb < 4; ++nb)
            #pragma unroll
            for (int ks = 0; ks < 2; ++ks)
                bfr[nb][ks] = *(const bf16x8*)(Wr + (nb * 16 + frow) * 128 + ks * 64 + kgrp * 16);

        int e0, e1;
        const bool isroot = (item == 20);
        if (!isroot) {
            e0 = offs[item * NN + n0];
            e1 = offs[item * NN + nend];
        } else {
            e0 = 0;
            e1 = nend - n0;
        }
        int ng = (e1 - e0 + 15) >> 4;

        for (int g = 0; g < ng; ++g) {
            // per-row metadata (all lanes hold row frow's entry)
            uint2 p;
            if (!isroot) {
                int e = e0 + g * 16 + frow;
                p = (e < e1) ? ep[e] : make_uint2(0u, 0u);
            } else {
                int rl = g * 16 + frow;
                p = (rl < e1) ? make_uint2((unsigned)(n0 + rl) | ((unsigned)rl << 20),
                                           __float_as_uint(1.0f))
                              : make_uint2(0u, 0u);
            }
            // A-fragments straight from global h
            int srcn = p.x & 0xFFFFF;
            const char* hrow = (const char*)hin + (size_t)srcn * 128;
            bf16x8 a0 = *(const bf16x8*)(hrow + kgrp * 16);
            bf16x8 a1 = *(const bf16x8*)(hrow + 64 + kgrp * 16);

            // D-row metadata for rows kgrp*4+j via cross-lane (lanes 0..15 hold rows)
            unsigned pd[4];
            float icd[4];
            #pragma unroll
            for (int j = 0; j < 4; ++j) {
                int srl = kgrp * 4 + j;
                pd[j]  = (unsigned)__shfl((int)p.x, srl);
                icd[j] = __uint_as_float(__shfl((int)p.y, srl));
            }

            f32x4 d[4];
            #pragma unroll
            for (int nb = 0; nb < 4; ++nb) {
                f32x4 z = {0.f, 0.f, 0.f, 0.f};
                z = __builtin_amdgcn_mfma_f32_16x16x32_bf16(a0, bfr[nb][0], z, 0, 0, 0);
                z = __builtin_amdgcn_mfma_f32_16x16x32_bf16(a1, bfr[nb][1], z, 0, 0, 0);
                d[nb] = z;
            }

            #pragma unroll
            for (int j = 0; j < 4; ++j) {
                int dl = (pd[j] >> 20) & 31;
                float ic = icd[j];
                float* orow = &ot[dl * ST + frow];
                #pragma unroll
                for (int nb = 0; nb < 4; ++nb)
                    atomicAdd(orow + nb * 16, d[nb][j] * ic);
            }
        }
    }
    __syncthreads();

    // epilogue: bias + BN (+ReLU). thread: row = tid>>3, cols c0..c0+7
    int row = tid >> 3;
    int c0  = (tid & 7) * 8;
    int node = n0 + row;
    if (node < NN) {
        float v[8];
        #pragma unroll
        for (int j = 0; j < 8; ++j) {
            int col = c0 + j;
            float s = ot[row * ST + col];
            float sc = gamma[col] * rsqrtf(rvar[col] + BN_EPS);
            v[j] = (s + bias[col] - rmean[col]) * sc + beta[col];
        }
        if (LAST) {
            float4 o0, o1;
            o0.x = fmaxf(v[0], 0.f); o0.y = fmaxf(v[1], 0.f);
            o0.z = fmaxf(v[2], 0.f); o0.w = fmaxf(v[3], 0.f);
            o1.x = fmaxf(v[4], 0.f); o1.y = fmaxf(v[5], 0.f);
            o1.z = fmaxf(v[6], 0.f); o1.w = fmaxf(v[7], 0.f);
            *(float4*)&outf[(size_t)node * 64 + c0]     = o0;
            *(float4*)&outf[(size_t)node * 64 + c0 + 4] = o1;
        } else {
            ushort4 p0, p1;
            p0.x = f2bf(v[0]); p0.y = f2bf(v[1]); p0.z = f2bf(v[2]); p0.w = f2bf(v[3]);
            p1.x = f2bf(v[4]); p1.y = f2bf(v[5]); p1.z = f2bf(v[6]); p1.w = f2bf(v[7]);
            *(ushort4*)&outb[(size_t)node * 64 + c0]     = p0;
            *(ushort4*)&outb[(size_t)node * 64 + c0 + 4] = p1;
        }
    }
}

extern "C" void kernel_launch(void* const* d_in, const int* in_sizes, int n_in,
                              void* d_out, int out_size, void* d_ws, size_t ws_size,
                              hipStream_t stream) {
    const float* x     = (const float*)d_in[0];
    const int*   ei    = (const int*)d_in[1];
    const int*   et    = (const int*)d_in[2];
    const float* W0    = (const float*)d_in[3];
    const float* root0 = (const float*)d_in[4];
    const float* b0    = (const float*)d_in[5];
    const float* Wh    = (const float*)d_in[6];
    const float* rooth = (const float*)d_in[7];
    const float* bh    = (const float*)d_in[8];
    const float* gamma = (const float*)d_in[9];
    const float* beta  = (const float*)d_in[10];
    const float* rmean = (const float*)d_in[11];
    const float* rvar  = (const float*)d_in[12];
    float* out = (float*)d_out;

    const int* src = ei;
    const int* dst = ei + NE;

    // workspace (~34 MB)
    int*   fill  = (int*)d_ws;                       // 1,000,000
    int*   offs  = fill + 1000000;                   // 1,000,004
    int*   bsums = offs + 1000004;                   // 1,024
    uint2* ep    = (uint2*)(bsums + 1024);           // 1,600,000 x 8B
    unsigned short* Wt = (unsigned short*)(ep + 1600000);   // 3*21*4096 bf16
    unsigned short* h0 = Wt + 3 * 21 * 4096;         // N*64 bf16
    unsigned short* h1 = h0 + NN * 64;               // N*64 bf16

    // ---- CSR build, (rel, dst)-ordered ----
    hipMemsetAsync(fill, 0, (size_t)SEGS * sizeof(int), stream);
    count_kernel<<<2048, 256, 0, stream>>>(dst, et, fill);
    scan1_kernel<<<SCAN_NB, 256, 0, stream>>>(fill, offs, bsums, SEGS);
    scan_top_kernel<<<1, 1024, 0, stream>>>(bsums, SCAN_NB);
    scan_add_kernel<<<2048, 256, 0, stream>>>(offs, bsums, SEGS);
    set_total_kernel<<<1, 1, 0, stream>>>(offs);
    hipMemsetAsync(fill, 0, (size_t)SEGS * sizeof(int), stream);
    fill_kernel<<<2048, 256, 0, stream>>>(src, dst, et, offs, fill, ep);
    wprep_kernel<<<63, 256, 0, stream>>>(Wh, rooth, Wt);

    const int GB = (NN + 31) / 32;   // 1563 blocks

    rgcn_l0<<<GB, 256, 0, stream>>>(
        x, offs, ep, W0, root0, b0, gamma, beta, rmean, rvar, h0);
    rgcn_hidden<false><<<GB, 256, 0, stream>>>(
        h0, offs, ep, Wt, bh, gamma + 64, beta + 64, rmean + 64, rvar + 64,
        h1, nullptr);
    rgcn_hidden<false><<<GB, 256, 0, stream>>>(
        h1, offs, ep, Wt + 21 * 4096, bh + 64, gamma + 128, beta + 128,
        rmean + 128, rvar + 128, h0, nullptr);
    rgcn_hidden<true><<<GB, 256, 0, stream>>>(
        h0, offs, ep, Wt + 42 * 4096, bh + 128, gamma + 192, beta + 192,
        rmean + 192, rvar + 192, nullptr, out);
}

// Round 6
// 945.634 us; speedup vs baseline: 2.5615x; 2.5615x over previous
//
#include <hip/hip_runtime.h>

#define NN 50000
#define NE 1600000
#define RR 20
#define BN_EPS 1e-5f
#define SEGS (NN * RR)                    /* 1,000,000 */
#define SCAN_NB ((SEGS + 1023) / 1024)    /* 977 */

typedef __attribute__((ext_vector_type(8))) short bf16x8;
typedef __attribute__((ext_vector_type(4))) float f32x4;

__device__ __forceinline__ unsigned short f2bf(float f) {
    unsigned u = __float_as_uint(f);
    u += 0x7fff + ((u >> 16) & 1);        // RNE
    return (unsigned short)(u >> 16);
}
__device__ __forceinline__ void unpack8(uint4 r, float* v) {
    v[0] = __uint_as_float(r.x << 16); v[1] = __uint_as_float(r.x & 0xffff0000u);
    v[2] = __uint_as_float(r.y << 16); v[3] = __uint_as_float(r.y & 0xffff0000u);
    v[4] = __uint_as_float(r.z << 16); v[5] = __uint_as_float(r.z & 0xffff0000u);
    v[6] = __uint_as_float(r.w << 16); v[7] = __uint_as_float(r.w & 0xffff0000u);
}

// ---------------- CSR build: count per (dst, rel) segment [dst-major] ----------------
__global__ void count_kernel(const int* __restrict__ dst, const int* __restrict__ et,
                             int* __restrict__ cnt) {
    int stride = gridDim.x * blockDim.x;
    for (int e = blockIdx.x * blockDim.x + threadIdx.x; e < NE; e += stride)
        atomicAdd(&cnt[dst[e] * RR + et[e]], 1);
}

__global__ __launch_bounds__(256) void scan1_kernel(const int* __restrict__ in,
                                                    int* __restrict__ out,
                                                    int* __restrict__ bsums, int n) {
    __shared__ int lds[256];
    int tid  = threadIdx.x;
    int base = blockIdx.x * 1024 + tid * 4;
    int v[4];
    #pragma unroll
    for (int j = 0; j < 4; ++j) v[j] = (base + j < n) ? in[base + j] : 0;
    int tsum = v[0] + v[1] + v[2] + v[3];
    lds[tid] = tsum;
    __syncthreads();
    for (int off = 1; off < 256; off <<= 1) {
        int t = (tid >= off) ? lds[tid - off] : 0;
        __syncthreads();
        lds[tid] += t;
        __syncthreads();
    }
    int run = lds[tid] - tsum;
    #pragma unroll
    for (int j = 0; j < 4; ++j) {
        if (base + j < n) out[base + j] = run;
        run += v[j];
    }
    if (tid == 255) bsums[blockIdx.x] = lds[255];
}

__global__ __launch_bounds__(1024) void scan_top_kernel(int* __restrict__ bsums, int nb) {
    __shared__ int lds[1024];
    int tid = threadIdx.x;
    int v = (tid < nb) ? bsums[tid] : 0;
    lds[tid] = v;
    __syncthreads();
    for (int off = 1; off < 1024; off <<= 1) {
        int t = (tid >= off) ? lds[tid - off] : 0;
        __syncthreads();
        lds[tid] += t;
        __syncthreads();
    }
    bsums[tid] = lds[tid] - v;
}

__global__ void scan_add_kernel(int* __restrict__ out, const int* __restrict__ bsums, int n) {
    int stride = gridDim.x * blockDim.x;
    for (int i = blockIdx.x * blockDim.x + threadIdx.x; i < n; i += stride)
        out[i] += bsums[i >> 10];
}

__global__ void set_total_kernel(int* __restrict__ offs) { offs[SEGS] = NE; }

// ------- bucket-fill: ep = {src | rel<<20, inv_cnt}, sorted by (dst, rel) ----------
__global__ void fill_kernel(const int* __restrict__ src, const int* __restrict__ dst,
                            const int* __restrict__ et, const int* __restrict__ offs,
                            int* __restrict__ fill, uint2* __restrict__ ep) {
    int stride = gridDim.x * blockDim.x;
    for (int e = blockIdx.x * blockDim.x + threadIdx.x; e < NE; e += stride) {
        int seg = dst[e] * RR + et[e];
        int pos = offs[seg] + atomicAdd(&fill[seg], 1);
        float ic = 1.0f / fmaxf((float)(offs[seg + 1] - offs[seg]), 1.0f);
        ep[pos] = make_uint2((unsigned)src[e] | ((unsigned)et[e] << 20),
                             __float_as_uint(ic));
    }
}

// ------- weight prep: Wt[l][item][n][k] bf16 (transposed), item 20 = root ---------
__global__ __launch_bounds__(256) void wprep_kernel(const float* __restrict__ Wh,
                                                    const float* __restrict__ rooth,
                                                    unsigned short* __restrict__ Wt) {
    int l = blockIdx.x / 21, r = blockIdx.x % 21;
    const float* Ws = (r < 20) ? Wh + ((size_t)l * 20 + r) * 4096
                               : rooth + (size_t)l * 4096;
    unsigned short* Wd = Wt + ((size_t)l * 21 + r) * 4096;
    int t = threadIdx.x;
    int n4 = (t & 15) * 4;
    for (int k = t >> 4; k < 64; k += 16) {
        float4 w = *(const float4*)&Ws[(size_t)k * 64 + n4];
        Wd[(n4 + 0) * 64 + k] = f2bf(w.x);
        Wd[(n4 + 1) * 64 + k] = f2bf(w.y);
        Wd[(n4 + 2) * 64 + k] = f2bf(w.z);
        Wd[(n4 + 3) * 64 + k] = f2bf(w.w);
    }
}

// ---------------- layer 0: wave-per-node direct compute (K=4), out bf16 -----------
__global__ __launch_bounds__(256) void rgcn_l0(
    const float* __restrict__ x, const int* __restrict__ offs,
    const uint2* __restrict__ ep,
    const float* __restrict__ W0, const float* __restrict__ root0,
    const float* __restrict__ b0, const float* __restrict__ gamma,
    const float* __restrict__ beta, const float* __restrict__ rmean,
    const float* __restrict__ rvar, unsigned short* __restrict__ outb) {
    int wid  = (blockIdx.x * 256 + threadIdx.x) >> 6;
    int nw   = (gridDim.x * 256) >> 6;
    int lane = threadIdx.x & 63;
    float sc = gamma[lane] * rsqrtf(rvar[lane] + BN_EPS);
    float sh = beta[lane] - rmean[lane] * sc;
    float bi = b0[lane];
    float r0 = root0[lane], r1 = root0[64 + lane];
    float r2 = root0[128 + lane], r3 = root0[192 + lane];
    for (int n = wid; n < NN; n += nw) {
        float acc = 0.f;
        int e    = offs[n * RR];
        int eend = offs[n * RR + RR];
        for (; e < eend; ++e) {
            uint2 m = ep[e];
            int s = m.x & 0xFFFFF;
            int r = m.x >> 20;
            float ic = __uint_as_float(m.y);
            float4 xv = *(const float4*)&x[(size_t)s * 4];
            const float* Wr = W0 + r * 256;
            acc += ic * (xv.x * Wr[lane] + xv.y * Wr[64 + lane] +
                         xv.z * Wr[128 + lane] + xv.w * Wr[192 + lane]);
        }
        float4 xn = *(const float4*)&x[(size_t)n * 4];
        acc += xn.x * r0 + xn.y * r1 + xn.z * r2 + xn.w * r3;
        outb[(size_t)n * 64 + lane] = f2bf((acc + bi) * sc + sh);
    }
}

// ---------------- transform: T[r-c0][n][:] = h[n][:] @ W_item(c0+r), bf16 out -------
__global__ __launch_bounds__(256) void xform_kernel(
    const unsigned short* __restrict__ hin, const unsigned short* __restrict__ WtL,
    unsigned short* __restrict__ T, int c0, int nr) {
    const int n0   = blockIdx.x * 64;
    const int wv   = threadIdx.x >> 6;
    const int lane = threadIdx.x & 63;
    const int frow = lane & 15;
    const int kgrp = lane >> 4;
    int arow = n0 + wv * 16 + frow;
    int arc  = min(arow, NN - 1);
    bf16x8 a0 = *(const bf16x8*)&hin[(size_t)arc * 64 + kgrp * 8];
    bf16x8 a1 = *(const bf16x8*)&hin[(size_t)arc * 64 + 32 + kgrp * 8];
    for (int r = 0; r < nr; ++r) {
        const unsigned short* Wr = WtL + (size_t)(c0 + r) * 4096;
        unsigned short* Tr = T + (size_t)r * NN * 64;
        #pragma unroll
        for (int cf = 0; cf < 4; ++cf) {
            bf16x8 b0 = *(const bf16x8*)&Wr[(cf * 16 + frow) * 64 + kgrp * 8];
            bf16x8 b1 = *(const bf16x8*)&Wr[(cf * 16 + frow) * 64 + 32 + kgrp * 8];
            f32x4 d = {0.f, 0.f, 0.f, 0.f};
            d = __builtin_amdgcn_mfma_f32_16x16x32_bf16(a0, b0, d, 0, 0, 0);
            d = __builtin_amdgcn_mfma_f32_16x16x32_bf16(a1, b1, d, 0, 0, 0);
            #pragma unroll
            for (int j = 0; j < 4; ++j) {
                int node = n0 + wv * 16 + kgrp * 4 + j;
                if (node < NN)
                    Tr[(size_t)node * 64 + cf * 16 + frow] = f2bf(d[j]);
            }
        }
    }
}

// ---------------- aggregate: out[n] = sum_e ic*T[rel][src] (+root, +accum, +BN) -----
// Wave handles 2 nodes; 8 edge-slots x 8-feature-lanes; 16 gathers in flight/iter.
template <bool FIRST, bool LASTP, bool LASTL>
__global__ __launch_bounds__(256) void agg_kernel(
    const unsigned short* __restrict__ T, const int* __restrict__ offs,
    const uint2* __restrict__ ep, float* __restrict__ accum, int c0, int c1,
    const float* __restrict__ bias, const float* __restrict__ gamma,
    const float* __restrict__ beta, const float* __restrict__ rmean,
    const float* __restrict__ rvar, unsigned short* __restrict__ outb,
    float* __restrict__ outf) {
    int wid   = (blockIdx.x * 256 + threadIdx.x) >> 6;
    int nw    = (gridDim.x * 256) >> 6;
    int lane  = threadIdx.x & 63;
    int eslot = lane >> 3;
    int flane = lane & 7;
    const int ce = (c1 < RR) ? c1 : RR;

    for (int pr = wid; pr * 2 < NN; pr += nw) {
        int nA = pr * 2, nB = pr * 2 + 1;
        int eA  = offs[nA * RR + c0] + eslot;
        int eA1 = offs[nA * RR + ce];
        int eB  = offs[nB * RR + c0] + eslot;
        int eB1 = offs[nB * RR + ce];
        float aA[8] = {0,0,0,0,0,0,0,0}, aB[8] = {0,0,0,0,0,0,0,0};

        while (eA < eA1 || eB < eB1) {
            if (eA < eA1) {
                uint2 m = ep[eA];
                float ic = __uint_as_float(m.y);
                size_t ti = ((size_t)((m.x >> 20) - c0) * NN + (m.x & 0xFFFFF)) * 64;
                uint4 row = *(const uint4*)&T[ti + flane * 8];
                float v[8]; unpack8(row, v);
                #pragma unroll
                for (int j = 0; j < 8; ++j) aA[j] += ic * v[j];
            }
            if (eB < eB1) {
                uint2 m = ep[eB];
                float ic = __uint_as_float(m.y);
                size_t ti = ((size_t)((m.x >> 20) - c0) * NN + (m.x & 0xFFFFF)) * 64;
                uint4 row = *(const uint4*)&T[ti + flane * 8];
                float v[8]; unpack8(row, v);
                #pragma unroll
                for (int j = 0; j < 8; ++j) aB[j] += ic * v[j];
            }
            eA += 8; eB += 8;
        }

        // reduce across the 8 edge-slots (xor over lane bits 3,4,5)
        #pragma unroll
        for (int off = 8; off < 64; off <<= 1) {
            #pragma unroll
            for (int j = 0; j < 8; ++j) {
                aA[j] += __shfl_xor(aA[j], off);
                aB[j] += __shfl_xor(aB[j], off);
            }
        }

        if (eslot == 0) {
            #pragma unroll
            for (int half = 0; half < 2; ++half) {
                int n = half ? nB : nA;
                float* a = half ? aB : aA;
                if (LASTP) {   // root item (index 20) lives in this chunk
                    uint4 rr = *(const uint4*)&T[((size_t)(20 - c0) * NN + n) * 64 + flane * 8];
                    float rv[8]; unpack8(rr, rv);
                    #pragma unroll
                    for (int j = 0; j < 8; ++j) a[j] += rv[j];
                }
                if (!FIRST) {
                    float4 p0 = *(const float4*)&accum[(size_t)n * 64 + flane * 8];
                    float4 p1 = *(const float4*)&accum[(size_t)n * 64 + flane * 8 + 4];
                    a[0] += p0.x; a[1] += p0.y; a[2] += p0.z; a[3] += p0.w;
                    a[4] += p1.x; a[5] += p1.y; a[6] += p1.z; a[7] += p1.w;
                }
                if (!LASTP) {
                    *(float4*)&accum[(size_t)n * 64 + flane * 8] =
                        make_float4(a[0], a[1], a[2], a[3]);
                    *(float4*)&accum[(size_t)n * 64 + flane * 8 + 4] =
                        make_float4(a[4], a[5], a[6], a[7]);
                } else {
                    float v[8];
                    #pragma unroll
                    for (int j = 0; j < 8; ++j) {
                        int col = flane * 8 + j;
                        float s = gamma[col] * rsqrtf(rvar[col] + BN_EPS);
                        v[j] = (a[j] + bias[col] - rmean[col]) * s + beta[col];
                    }
                    if (LASTL) {
                        float4 o0 = make_float4(fmaxf(v[0],0.f), fmaxf(v[1],0.f),
                                                fmaxf(v[2],0.f), fmaxf(v[3],0.f));
                        float4 o1 = make_float4(fmaxf(v[4],0.f), fmaxf(v[5],0.f),
                                                fmaxf(v[6],0.f), fmaxf(v[7],0.f));
                        *(float4*)&outf[(size_t)n * 64 + flane * 8]     = o0;
                        *(float4*)&outf[(size_t)n * 64 + flane * 8 + 4] = o1;
                    } else {
                        ushort4 p0, p1;
                        p0.x = f2bf(v[0]); p0.y = f2bf(v[1]);
                        p0.z = f2bf(v[2]); p0.w = f2bf(v[3]);
                        p1.x = f2bf(v[4]); p1.y = f2bf(v[5]);
                        p1.z = f2bf(v[6]); p1.w = f2bf(v[7]);
                        *(ushort4*)&outb[(size_t)n * 64 + flane * 8]     = p0;
                        *(ushort4*)&outb[(size_t)n * 64 + flane * 8 + 4] = p1;
                    }
                }
            }
        }
    }
}

extern "C" void kernel_launch(void* const* d_in, const int* in_sizes, int n_in,
                              void* d_out, int out_size, void* d_ws, size_t ws_size,
                              hipStream_t stream) {
    const float* x     = (const float*)d_in[0];
    const int*   ei    = (const int*)d_in[1];
    const int*   et    = (const int*)d_in[2];
    const float* W0    = (const float*)d_in[3];
    const float* root0 = (const float*)d_in[4];
    const float* b0    = (const float*)d_in[5];
    const float* Wh    = (const float*)d_in[6];
    const float* rooth = (const float*)d_in[7];
    const float* bh    = (const float*)d_in[8];
    const float* gamma = (const float*)d_in[9];
    const float* beta  = (const float*)d_in[10];
    const float* rmean = (const float*)d_in[11];
    const float* rvar  = (const float*)d_in[12];
    float* out = (float*)d_out;

    const int* src = ei;
    const int* dst = ei + NE;

    // workspace layout (fixed part ≈ 43.5 MB, then T chunk)
    int*   fill  = (int*)d_ws;                        // SEGS
    int*   offs  = fill + SEGS;                       // SEGS+4
    int*   bsums = offs + SEGS + 4;                   // 1024
    uint2* ep    = (uint2*)(bsums + 1024);            // NE x 8B
    unsigned short* Wt = (unsigned short*)(ep + NE);  // 3*21*4096
    unsigned short* h0 = Wt + 3 * 21 * 4096;          // N*64
    unsigned short* h1 = h0 + NN * 64;                // N*64
    float* accum = (float*)(h1 + NN * 64);            // N*64 fp32
    unsigned short* T = (unsigned short*)(accum + NN * 64);

    size_t used  = (size_t)((char*)T - (char*)d_ws);
    size_t avail = (ws_size > used) ? ws_size - used : 0;
    size_t per   = (size_t)NN * 64 * 2;
    int nrel = (int)(avail / per);
    if (nrel < 1) nrel = 1;
    if (nrel > 21) nrel = 21;
    int npass = (21 + nrel - 1) / nrel;

    // ---- CSR build, (dst, rel)-ordered ----
    hipMemsetAsync(fill, 0, (size_t)SEGS * sizeof(int), stream);
    count_kernel<<<2048, 256, 0, stream>>>(dst, et, fill);
    scan1_kernel<<<SCAN_NB, 256, 0, stream>>>(fill, offs, bsums, SEGS);
    scan_top_kernel<<<1, 1024, 0, stream>>>(bsums, SCAN_NB);
    scan_add_kernel<<<2048, 256, 0, stream>>>(offs, bsums, SEGS);
    set_total_kernel<<<1, 1, 0, stream>>>(offs);
    hipMemsetAsync(fill, 0, (size_t)SEGS * sizeof(int), stream);
    fill_kernel<<<2048, 256, 0, stream>>>(src, dst, et, offs, fill, ep);
    wprep_kernel<<<63, 256, 0, stream>>>(Wh, rooth, Wt);

    // ---- layer 0 ----
    rgcn_l0<<<1024, 256, 0, stream>>>(
        x, offs, ep, W0, root0, b0, gamma, beta, rmean, rvar, h0);

    // ---- layers 1..3: chunked transform + aggregate ----
    const int XB = (NN + 63) / 64;   // 782
    for (int l = 1; l <= 3; ++l) {
        const unsigned short* hin = (l == 2) ? h1 : h0;
        unsigned short* hout = (l == 1) ? h1 : h0;
        const unsigned short* WtL = Wt + (size_t)(l - 1) * 21 * 4096;
        const float* bl  = bh + (size_t)(l - 1) * 64;
        const float* gl  = gamma + (size_t)l * 64;
        const float* btl = beta + (size_t)l * 64;
        const float* rml = rmean + (size_t)l * 64;
        const float* rvl = rvar + (size_t)l * 64;
        int c0 = 0;
        for (int p = 0; p < npass; ++p) {
            int c1 = c0 + nrel; if (c1 > 21) c1 = 21;
            xform_kernel<<<XB, 256, 0, stream>>>(hin, WtL, T, c0, c1 - c0);
            bool first = (p == 0), lastp = (p == npass - 1);
            bool lastl = lastp && (l == 3);
            #define AGG(F, LP, LL) agg_kernel<F, LP, LL><<<1024, 256, 0, stream>>>( \
                T, offs, ep, accum, c0, c1, bl, gl, btl, rml, rvl, hout, out)
            if (first && lastp && lastl)      AGG(true,  true,  true);
            else if (first && lastp)          AGG(true,  true,  false);
            else if (first)                   AGG(true,  false, false);
            else if (lastp && lastl)          AGG(false, true,  true);
            else if (lastp)                   AGG(false, true,  false);
            else                              AGG(false, false, false);
            #undef AGG
            c0 = c1;
        }
    }
}

// Round 7
// 791.299 us; speedup vs baseline: 3.0610x; 1.1950x over previous
//
#include <hip/hip_runtime.h>

#define NN 50000
#define NE 1600000
#define RR 20
#define BN_EPS 1e-5f
#define SCAN_NB ((NN + 1023) / 1024)   /* 49 */

typedef __attribute__((ext_vector_type(8))) short bf16x8;
typedef __attribute__((ext_vector_type(4))) float f32x4;

__device__ __forceinline__ unsigned short f2bf(float f) {
    unsigned u = __float_as_uint(f);
    u += 0x7fff + ((u >> 16) & 1);        // RNE
    return (unsigned short)(u >> 16);
}
__device__ __forceinline__ void unpack8(uint4 r, float* v) {
    v[0] = __uint_as_float(r.x << 16); v[1] = __uint_as_float(r.x & 0xffff0000u);
    v[2] = __uint_as_float(r.y << 16); v[3] = __uint_as_float(r.y & 0xffff0000u);
    v[4] = __uint_as_float(r.z << 16); v[5] = __uint_as_float(r.z & 0xffff0000u);
    v[6] = __uint_as_float(r.w << 16); v[7] = __uint_as_float(r.w & 0xffff0000u);
}

// ---------------- (dst,rel) histogram (for inv_cnt) ----------------
__global__ void count_kernel(const int* __restrict__ dst, const int* __restrict__ et,
                             int* __restrict__ cnt) {
    int stride = gridDim.x * blockDim.x;
    for (int e = blockIdx.x * blockDim.x + threadIdx.x; e < NE; e += stride)
        atomicAdd(&cnt[dst[e] * RR + et[e]], 1);
}

// ---------------- per-dst degree = row-sum of histogram ----------------
__global__ void deg_kernel(const int* __restrict__ cnt, int* __restrict__ deg) {
    int stride = gridDim.x * blockDim.x;
    for (int n = blockIdx.x * blockDim.x + threadIdx.x; n < NN; n += stride) {
        int s = 0;
        #pragma unroll
        for (int r = 0; r < RR; ++r) s += cnt[n * RR + r];
        deg[n] = s;
    }
}

// ---------------- exclusive scan over NN entries (3 kernels) ----------------
__global__ __launch_bounds__(256) void scan1_kernel(const int* __restrict__ in,
                                                    int* __restrict__ out,
                                                    int* __restrict__ bsums, int n) {
    __shared__ int lds[256];
    int tid  = threadIdx.x;
    int base = blockIdx.x * 1024 + tid * 4;
    int v[4];
    #pragma unroll
    for (int j = 0; j < 4; ++j) v[j] = (base + j < n) ? in[base + j] : 0;
    int tsum = v[0] + v[1] + v[2] + v[3];
    lds[tid] = tsum;
    __syncthreads();
    for (int off = 1; off < 256; off <<= 1) {
        int t = (tid >= off) ? lds[tid - off] : 0;
        __syncthreads();
        lds[tid] += t;
        __syncthreads();
    }
    int run = lds[tid] - tsum;
    #pragma unroll
    for (int j = 0; j < 4; ++j) {
        if (base + j < n) out[base + j] = run;
        run += v[j];
    }
    if (tid == 255) bsums[blockIdx.x] = lds[255];
}

__global__ __launch_bounds__(1024) void scan_top_kernel(int* __restrict__ bsums, int nb) {
    __shared__ int lds[1024];
    int tid = threadIdx.x;
    int v = (tid < nb) ? bsums[tid] : 0;
    lds[tid] = v;
    __syncthreads();
    for (int off = 1; off < 1024; off <<= 1) {
        int t = (tid >= off) ? lds[tid - off] : 0;
        __syncthreads();
        lds[tid] += t;
        __syncthreads();
    }
    bsums[tid] = lds[tid] - v;
}

__global__ void scan_add_kernel(int* __restrict__ out, const int* __restrict__ bsums, int n) {
    int stride = gridDim.x * blockDim.x;
    int i = blockIdx.x * blockDim.x + threadIdx.x;
    if (i == 0) out[NN] = NE;
    for (; i < n; i += stride)
        out[i] += bsums[i >> 10];
}

// ------- bucket-fill: ep = {src | rel<<20, inv_cnt}, grouped by dst ----------
__global__ void fill_kernel(const int* __restrict__ src, const int* __restrict__ dst,
                            const int* __restrict__ et, const int* __restrict__ offs,
                            const int* __restrict__ cntdr,
                            int* __restrict__ fill, uint2* __restrict__ ep) {
    int stride = gridDim.x * blockDim.x;
    for (int e = blockIdx.x * blockDim.x + threadIdx.x; e < NE; e += stride) {
        int d = dst[e], r = et[e];
        int pos = offs[d] + atomicAdd(&fill[d], 1);
        int c = cntdr[d * RR + r];
        float ic = 1.0f / (float)(c > 0 ? c : 1);
        ep[pos] = make_uint2((unsigned)src[e] | ((unsigned)r << 20),
                             __float_as_uint(ic));
    }
}

// ------- weight prep: Wt[l][item][n][k] bf16 (transposed), item 20 = root ---------
__global__ __launch_bounds__(256) void wprep_kernel(const float* __restrict__ Wh,
                                                    const float* __restrict__ rooth,
                                                    unsigned short* __restrict__ Wt) {
    int l = blockIdx.x / 21, r = blockIdx.x % 21;
    const float* Ws = (r < 20) ? Wh + ((size_t)l * 20 + r) * 4096
                               : rooth + (size_t)l * 4096;
    unsigned short* Wd = Wt + ((size_t)l * 21 + r) * 4096;
    int t = threadIdx.x;
    int n4 = (t & 15) * 4;
    for (int k = t >> 4; k < 64; k += 16) {
        float4 w = *(const float4*)&Ws[(size_t)k * 64 + n4];
        Wd[(n4 + 0) * 64 + k] = f2bf(w.x);
        Wd[(n4 + 1) * 64 + k] = f2bf(w.y);
        Wd[(n4 + 2) * 64 + k] = f2bf(w.z);
        Wd[(n4 + 3) * 64 + k] = f2bf(w.w);
    }
}

// ---------------- layer-0 transform: T[item][n][col] = x[n] . W0_item ----------------
__global__ __launch_bounds__(256) void xform0_kernel(
    const float* __restrict__ x, const float* __restrict__ W0,
    const float* __restrict__ root0, unsigned short* __restrict__ T,
    int c0, int nr) {
    __shared__ float Wl[21 * 256];
    int tid = threadIdx.x;
    for (int i = tid; i < 21 * 256; i += 256)
        Wl[i] = (i < 20 * 256) ? W0[i] : root0[i - 20 * 256];
    __syncthreads();
    int wslot = (blockIdx.x * 256 + tid) >> 6;
    int nw    = (gridDim.x * 256) >> 6;
    int col   = tid & 63;
    for (int n = wslot; n < NN; n += nw) {
        float4 xv = *(const float4*)&x[(size_t)n * 4];
        for (int r = 0; r < nr; ++r) {
            const float* w = &Wl[(c0 + r) * 256];
            float acc = xv.x * w[col] + xv.y * w[64 + col] +
                        xv.z * w[128 + col] + xv.w * w[192 + col];
            T[((size_t)r * NN + n) * 64 + col] = f2bf(acc);
        }
    }
}

// ---------------- hidden transform: T[item][n][:] = h[n][:] @ W_item (MFMA) ----------
// LDS-staged D so T writes are coalesced dwordx4 rows.
__global__ __launch_bounds__(256) void xform_kernel(
    const unsigned short* __restrict__ hin, const unsigned short* __restrict__ WtL,
    unsigned short* __restrict__ T, int c0, int nr) {
    __shared__ unsigned short tile[64 * 72];   // +8 col pad: 16B-aligned rows, fewer conflicts
    const int tid  = threadIdx.x;
    const int n0   = blockIdx.x * 64;
    const int wv   = tid >> 6;
    const int lane = tid & 63;
    const int frow = lane & 15;
    const int kgrp = lane >> 4;
    int arc = min(n0 + wv * 16 + frow, NN - 1);
    bf16x8 a0 = *(const bf16x8*)&hin[(size_t)arc * 64 + kgrp * 8];
    bf16x8 a1 = *(const bf16x8*)&hin[(size_t)arc * 64 + 32 + kgrp * 8];
    for (int r = 0; r < nr; ++r) {
        const unsigned short* Wr = WtL + (size_t)(c0 + r) * 4096;
        unsigned short* Tr = T + (size_t)r * NN * 64;
        #pragma unroll
        for (int cf = 0; cf < 4; ++cf) {
            bf16x8 b0 = *(const bf16x8*)&Wr[(cf * 16 + frow) * 64 + kgrp * 8];
            bf16x8 b1 = *(const bf16x8*)&Wr[(cf * 16 + frow) * 64 + 32 + kgrp * 8];
            f32x4 d = {0.f, 0.f, 0.f, 0.f};
            d = __builtin_amdgcn_mfma_f32_16x16x32_bf16(a0, b0, d, 0, 0, 0);
            d = __builtin_amdgcn_mfma_f32_16x16x32_bf16(a1, b1, d, 0, 0, 0);
            #pragma unroll
            for (int j = 0; j < 4; ++j)
                tile[(wv * 16 + kgrp * 4 + j) * 72 + cf * 16 + frow] = f2bf(d[j]);
        }
        __syncthreads();
        #pragma unroll
        for (int i = tid; i < 512; i += 256) {
            int row = i >> 3, c16 = i & 7;
            int node = n0 + row;
            if (node < NN)
                *(uint4*)&Tr[(size_t)node * 64 + c16 * 8] =
                    *(const uint4*)&tile[row * 72 + c16 * 8];
        }
        __syncthreads();
    }
}

// ---------------- aggregate: out[n] = sum_e ic*T[rel][src] (+root, +accum, +BN) -----
// One wave per node; 8 edge-slots x 8 feature-lanes.
template <bool FIRST, bool LASTP, bool LASTL>
__global__ __launch_bounds__(256) void agg_kernel(
    const unsigned short* __restrict__ T, const int* __restrict__ offs,
    const uint2* __restrict__ ep, float* __restrict__ accum, int c0, int c1,
    const float* __restrict__ bias, const float* __restrict__ gamma,
    const float* __restrict__ beta, const float* __restrict__ rmean,
    const float* __restrict__ rvar, unsigned short* __restrict__ outb,
    float* __restrict__ outf) {
    constexpr bool FULL = FIRST && LASTP;   // single pass: no rel filter needed
    int wid   = (blockIdx.x * 256 + threadIdx.x) >> 6;
    int nw    = (gridDim.x * 256) >> 6;
    int lane  = threadIdx.x & 63;
    int eslot = lane >> 3;
    int flane = lane & 7;
    const unsigned ce = (c1 < RR) ? (unsigned)c1 : (unsigned)RR;

    for (int n = wid; n < NN; n += nw) {
        int e0 = offs[n], e1 = offs[n + 1];
        float a[8] = {0, 0, 0, 0, 0, 0, 0, 0};
        for (int e = e0 + eslot; e < e1; e += 8) {
            uint2 m = ep[e];
            unsigned r = m.x >> 20;
            if (FULL || (r >= (unsigned)c0 && r < ce)) {
                float ic = __uint_as_float(m.y);
                size_t ti = ((size_t)(r - c0) * NN + (m.x & 0xFFFFF)) * 64;
                uint4 row = *(const uint4*)&T[ti + flane * 8];
                float v[8]; unpack8(row, v);
                #pragma unroll
                for (int j = 0; j < 8; ++j) a[j] += ic * v[j];
            }
        }
        #pragma unroll
        for (int off = 8; off < 64; off <<= 1)
            #pragma unroll
            for (int j = 0; j < 8; ++j) a[j] += __shfl_xor(a[j], off);

        if (eslot == 0) {
            if (LASTP) {   // root item (20) lives in the last chunk
                uint4 rr = *(const uint4*)&T[((size_t)(20 - c0) * NN + n) * 64 + flane * 8];
                float rv[8]; unpack8(rr, rv);
                #pragma unroll
                for (int j = 0; j < 8; ++j) a[j] += rv[j];
            }
            if (!FIRST) {
                float4 p0 = *(const float4*)&accum[(size_t)n * 64 + flane * 8];
                float4 p1 = *(const float4*)&accum[(size_t)n * 64 + flane * 8 + 4];
                a[0] += p0.x; a[1] += p0.y; a[2] += p0.z; a[3] += p0.w;
                a[4] += p1.x; a[5] += p1.y; a[6] += p1.z; a[7] += p1.w;
            }
            if (!LASTP) {
                *(float4*)&accum[(size_t)n * 64 + flane * 8] =
                    make_float4(a[0], a[1], a[2], a[3]);
                *(float4*)&accum[(size_t)n * 64 + flane * 8 + 4] =
                    make_float4(a[4], a[5], a[6], a[7]);
            } else {
                float v[8];
                #pragma unroll
                for (int j = 0; j < 8; ++j) {
                    int col = flane * 8 + j;
                    float s = gamma[col] * rsqrtf(rvar[col] + BN_EPS);
                    v[j] = (a[j] + bias[col] - rmean[col]) * s + beta[col];
                }
                if (LASTL) {
                    float4 o0 = make_float4(fmaxf(v[0],0.f), fmaxf(v[1],0.f),
                                            fmaxf(v[2],0.f), fmaxf(v[3],0.f));
                    float4 o1 = make_float4(fmaxf(v[4],0.f), fmaxf(v[5],0.f),
                                            fmaxf(v[6],0.f), fmaxf(v[7],0.f));
                    *(float4*)&outf[(size_t)n * 64 + flane * 8]     = o0;
                    *(float4*)&outf[(size_t)n * 64 + flane * 8 + 4] = o1;
                } else {
                    ushort4 p0, p1;
                    p0.x = f2bf(v[0]); p0.y = f2bf(v[1]);
                    p0.z = f2bf(v[2]); p0.w = f2bf(v[3]);
                    p1.x = f2bf(v[4]); p1.y = f2bf(v[5]);
                    p1.z = f2bf(v[6]); p1.w = f2bf(v[7]);
                    *(ushort4*)&outb[(size_t)n * 64 + flane * 8]     = p0;
                    *(ushort4*)&outb[(size_t)n * 64 + flane * 8 + 4] = p1;
                }
            }
        }
    }
}

extern "C" void kernel_launch(void* const* d_in, const int* in_sizes, int n_in,
                              void* d_out, int out_size, void* d_ws, size_t ws_size,
                              hipStream_t stream) {
    const float* x     = (const float*)d_in[0];
    const int*   ei    = (const int*)d_in[1];
    const int*   et    = (const int*)d_in[2];
    const float* W0    = (const float*)d_in[3];
    const float* root0 = (const float*)d_in[4];
    const float* b0    = (const float*)d_in[5];
    const float* Wh    = (const float*)d_in[6];
    const float* rooth = (const float*)d_in[7];
    const float* bh    = (const float*)d_in[8];
    const float* gamma = (const float*)d_in[9];
    const float* beta  = (const float*)d_in[10];
    const float* rmean = (const float*)d_in[11];
    const float* rvar  = (const float*)d_in[12];
    float* out = (float*)d_out;

    const int* src = ei;
    const int* dst = ei + NE;

    // workspace layout (fixed ≈ 43.5 MB, then T chunk up to 134.4 MB)
    int*   cntdr = (int*)d_ws;                        // 1,000,000
    int*   deg   = cntdr + 1000000;                   // 50,000
    int*   fill  = deg + 50000;                       // 50,000
    int*   offs  = fill + 50000;                      // 50,004
    int*   bsums = offs + 50004;                      // 1,024
    uint2* ep    = (uint2*)(bsums + 1024);            // NE x 8B
    unsigned short* Wt = (unsigned short*)(ep + NE);  // 3*21*4096
    unsigned short* h0 = Wt + 3 * 21 * 4096;          // N*64
    unsigned short* h1 = h0 + NN * 64;                // N*64
    float* accum = (float*)(h1 + NN * 64);            // N*64 fp32
    unsigned short* T = (unsigned short*)(accum + NN * 64);

    size_t used  = (size_t)((char*)T - (char*)d_ws);
    size_t avail = (ws_size > used) ? ws_size - used : 0;
    size_t per   = (size_t)NN * 64 * 2;
    int nrel = (int)(avail / per);
    if (nrel < 1) nrel = 1;
    if (nrel > 21) nrel = 21;
    int npass = (21 + nrel - 1) / nrel;

    // ---- CSR build: dst-grouped edges + (dst,rel) histogram for inv_cnt ----
    hipMemsetAsync(cntdr, 0, (size_t)NN * RR * sizeof(int), stream);
    hipMemsetAsync(fill, 0, (size_t)NN * sizeof(int), stream);
    count_kernel<<<2048, 256, 0, stream>>>(dst, et, cntdr);
    deg_kernel<<<256, 256, 0, stream>>>(cntdr, deg);
    scan1_kernel<<<SCAN_NB, 256, 0, stream>>>(deg, offs, bsums, NN);
    scan_top_kernel<<<1, 1024, 0, stream>>>(bsums, SCAN_NB);
    scan_add_kernel<<<256, 256, 0, stream>>>(offs, bsums, NN);
    fill_kernel<<<2048, 256, 0, stream>>>(src, dst, et, offs, cntdr, fill, ep);
    wprep_kernel<<<63, 256, 0, stream>>>(Wh, rooth, Wt);

    const int XB = (NN + 63) / 64;   // 782

    for (int l = 0; l < 4; ++l) {
        const unsigned short* hin = (l == 2) ? h1 : h0;   // l==1 uses h0, l==3 uses h0
        unsigned short* hout = (l == 1) ? h1 : h0;        // l0->h0, l1->h1, l2->h0
        const float* bl  = (l == 0) ? b0 : bh + (size_t)(l - 1) * 64;
        const float* gl  = gamma + (size_t)l * 64;
        const float* btl = beta + (size_t)l * 64;
        const float* rml = rmean + (size_t)l * 64;
        const float* rvl = rvar + (size_t)l * 64;
        int c0 = 0;
        for (int p = 0; p < npass; ++p) {
            int c1 = c0 + nrel; if (c1 > 21) c1 = 21;
            if (l == 0)
                xform0_kernel<<<2048, 256, 0, stream>>>(x, W0, root0, T, c0, c1 - c0);
            else
                xform_kernel<<<XB, 256, 0, stream>>>(
                    hin, Wt + (size_t)(l - 1) * 21 * 4096, T, c0, c1 - c0);
            bool first = (p == 0), lastp = (p == npass - 1);
            bool lastl = lastp && (l == 3);
            #define AGG(F, LP, LL) agg_kernel<F, LP, LL><<<2048, 256, 0, stream>>>( \
                T, offs, ep, accum, c0, c1, bl, gl, btl, rml, rvl, hout, out)
            if (first && lastp && lastl)      AGG(true,  true,  true);
            else if (first && lastp)          AGG(true,  true,  false);
            else if (first)                   AGG(true,  false, false);
            else if (lastp && lastl)          AGG(false, true,  true);
            else if (lastp)                   AGG(false, true,  false);
            else                              AGG(false, false, false);
            #undef AGG
            c0 = c1;
        }
    }
}

// Round 8
// 734.529 us; speedup vs baseline: 3.2976x; 1.0773x over previous
//
#include <hip/hip_runtime.h>

#define NN 50000
#define NE 1600000
#define RR 20
#define BN_EPS 1e-5f
#define SCAN_NB ((NN + 1023) / 1024)   /* 49 */

typedef __attribute__((ext_vector_type(8))) short bf16x8;
typedef __attribute__((ext_vector_type(4))) float f32x4;

__device__ __forceinline__ unsigned short f2bf(float f) {
    unsigned u = __float_as_uint(f);
    u += 0x7fff + ((u >> 16) & 1);        // RNE
    return (unsigned short)(u >> 16);
}
__device__ __forceinline__ void unpack8(uint4 r, float* v) {
    v[0] = __uint_as_float(r.x << 16); v[1] = __uint_as_float(r.x & 0xffff0000u);
    v[2] = __uint_as_float(r.y << 16); v[3] = __uint_as_float(r.y & 0xffff0000u);
    v[4] = __uint_as_float(r.z << 16); v[5] = __uint_as_float(r.z & 0xffff0000u);
    v[6] = __uint_as_float(r.w << 16); v[7] = __uint_as_float(r.w & 0xffff0000u);
}

// ---------------- (dst,rel) histogram (for inv_cnt) ----------------
__global__ void count_kernel(const int* __restrict__ dst, const int* __restrict__ et,
                             int* __restrict__ cnt) {
    int stride = gridDim.x * blockDim.x;
    for (int e = blockIdx.x * blockDim.x + threadIdx.x; e < NE; e += stride)
        atomicAdd(&cnt[dst[e] * RR + et[e]], 1);
}

// ---------------- per-dst degree = row-sum of histogram ----------------
__global__ void deg_kernel(const int* __restrict__ cnt, int* __restrict__ deg) {
    int stride = gridDim.x * blockDim.x;
    for (int n = blockIdx.x * blockDim.x + threadIdx.x; n < NN; n += stride) {
        int s = 0;
        #pragma unroll
        for (int r = 0; r < RR; ++r) s += cnt[n * RR + r];
        deg[n] = s;
    }
}

// ---------------- exclusive scan over NN entries ----------------
__global__ __launch_bounds__(256) void scan1_kernel(const int* __restrict__ in,
                                                    int* __restrict__ out,
                                                    int* __restrict__ bsums, int n) {
    __shared__ int lds[256];
    int tid  = threadIdx.x;
    int base = blockIdx.x * 1024 + tid * 4;
    int v[4];
    #pragma unroll
    for (int j = 0; j < 4; ++j) v[j] = (base + j < n) ? in[base + j] : 0;
    int tsum = v[0] + v[1] + v[2] + v[3];
    lds[tid] = tsum;
    __syncthreads();
    for (int off = 1; off < 256; off <<= 1) {
        int t = (tid >= off) ? lds[tid - off] : 0;
        __syncthreads();
        lds[tid] += t;
        __syncthreads();
    }
    int run = lds[tid] - tsum;
    #pragma unroll
    for (int j = 0; j < 4; ++j) {
        if (base + j < n) out[base + j] = run;
        run += v[j];
    }
    if (tid == 255) bsums[blockIdx.x] = lds[255];
}

__global__ __launch_bounds__(1024) void scan_top_kernel(int* __restrict__ bsums, int nb) {
    __shared__ int lds[1024];
    int tid = threadIdx.x;
    int v = (tid < nb) ? bsums[tid] : 0;
    lds[tid] = v;
    __syncthreads();
    for (int off = 1; off < 1024; off <<= 1) {
        int t = (tid >= off) ? lds[tid - off] : 0;
        __syncthreads();
        lds[tid] += t;
        __syncthreads();
    }
    bsums[tid] = lds[tid] - v;
}

__global__ void scan_add_kernel(int* __restrict__ out, const int* __restrict__ bsums, int n) {
    int stride = gridDim.x * blockDim.x;
    int i = blockIdx.x * blockDim.x + threadIdx.x;
    if (i == 0) out[NN] = NE;
    for (; i < n; i += stride)
        out[i] += bsums[i >> 10];
}

// ------- bucket-fill: ep = {src | rel<<20, inv_cnt}, grouped by dst ----------
__global__ void fill_kernel(const int* __restrict__ src, const int* __restrict__ dst,
                            const int* __restrict__ et, const int* __restrict__ offs,
                            const int* __restrict__ cntdr,
                            int* __restrict__ fill, uint2* __restrict__ ep) {
    int stride = gridDim.x * blockDim.x;
    for (int e = blockIdx.x * blockDim.x + threadIdx.x; e < NE; e += stride) {
        int d = dst[e], r = et[e];
        int pos = offs[d] + atomicAdd(&fill[d], 1);
        int c = cntdr[d * RR + r];
        float ic = 1.0f / (float)(c > 0 ? c : 1);
        ep[pos] = make_uint2((unsigned)src[e] | ((unsigned)r << 20),
                             __float_as_uint(ic));
    }
}

// ------- weight prep: Wt[l][item][n][k] bf16 (transposed), item 20 = root ---------
__global__ __launch_bounds__(256) void wprep_kernel(const float* __restrict__ Wh,
                                                    const float* __restrict__ rooth,
                                                    unsigned short* __restrict__ Wt) {
    int l = blockIdx.x / 21, r = blockIdx.x % 21;
    const float* Ws = (r < 20) ? Wh + ((size_t)l * 20 + r) * 4096
                               : rooth + (size_t)l * 4096;
    unsigned short* Wd = Wt + ((size_t)l * 21 + r) * 4096;
    int t = threadIdx.x;
    int n4 = (t & 15) * 4;
    for (int k = t >> 4; k < 64; k += 16) {
        float4 w = *(const float4*)&Ws[(size_t)k * 64 + n4];
        Wd[(n4 + 0) * 64 + k] = f2bf(w.x);
        Wd[(n4 + 1) * 64 + k] = f2bf(w.y);
        Wd[(n4 + 2) * 64 + k] = f2bf(w.z);
        Wd[(n4 + 3) * 64 + k] = f2bf(w.w);
    }
}

// -------- layer 0 fused: gather x[src], inline 4->64 transform, mean+root+BN --------
// One wave per node; 8 edge-slots x 8 feature-lanes; W0+root0 (21x256 f32) in LDS.
__global__ __launch_bounds__(256) void agg0_kernel(
    const float* __restrict__ x, const int* __restrict__ offs,
    const uint2* __restrict__ ep,
    const float* __restrict__ W0, const float* __restrict__ root0,
    const float* __restrict__ b0, const float* __restrict__ gamma,
    const float* __restrict__ beta, const float* __restrict__ rmean,
    const float* __restrict__ rvar, unsigned short* __restrict__ outb) {
    __shared__ float Wl[21 * 256];
    int tid = threadIdx.x;
    for (int i = tid; i < 21 * 256; i += 256)
        Wl[i] = (i < 20 * 256) ? W0[i] : root0[i - 20 * 256];
    __syncthreads();

    int wid   = (blockIdx.x * 256 + tid) >> 6;
    int nw    = (gridDim.x * 256) >> 6;
    int lane  = tid & 63;
    int eslot = lane >> 3;
    int flane = lane & 7;

    for (int n = wid; n < NN; n += nw) {
        int e0 = offs[n], e1 = offs[n + 1];
        float a[8] = {0, 0, 0, 0, 0, 0, 0, 0};
        for (int e = e0 + eslot; e < e1; e += 8) {
            uint2 m = ep[e];
            float ic = __uint_as_float(m.y);
            float4 xv = *(const float4*)&x[(size_t)(m.x & 0xFFFFF) * 4];
            const float* w = &Wl[(m.x >> 20) * 256 + flane * 8];
            float4 w0 = *(const float4*)&w[0],   w0b = *(const float4*)&w[4];
            float4 w1 = *(const float4*)&w[64],  w1b = *(const float4*)&w[68];
            float4 w2 = *(const float4*)&w[128], w2b = *(const float4*)&w[132];
            float4 w3 = *(const float4*)&w[192], w3b = *(const float4*)&w[196];
            a[0] += ic * (xv.x * w0.x + xv.y * w1.x + xv.z * w2.x + xv.w * w3.x);
            a[1] += ic * (xv.x * w0.y + xv.y * w1.y + xv.z * w2.y + xv.w * w3.y);
            a[2] += ic * (xv.x * w0.z + xv.y * w1.z + xv.z * w2.z + xv.w * w3.z);
            a[3] += ic * (xv.x * w0.w + xv.y * w1.w + xv.z * w2.w + xv.w * w3.w);
            a[4] += ic * (xv.x * w0b.x + xv.y * w1b.x + xv.z * w2b.x + xv.w * w3b.x);
            a[5] += ic * (xv.x * w0b.y + xv.y * w1b.y + xv.z * w2b.y + xv.w * w3b.y);
            a[6] += ic * (xv.x * w0b.z + xv.y * w1b.z + xv.z * w2b.z + xv.w * w3b.z);
            a[7] += ic * (xv.x * w0b.w + xv.y * w1b.w + xv.z * w2b.w + xv.w * w3b.w);
        }
        #pragma unroll
        for (int off = 8; off < 64; off <<= 1)
            #pragma unroll
            for (int j = 0; j < 8; ++j) a[j] += __shfl_xor(a[j], off);

        if (eslot == 0) {
            float4 xn = *(const float4*)&x[(size_t)n * 4];
            const float* w = &Wl[20 * 256 + flane * 8];
            float v[8];
            #pragma unroll
            for (int j = 0; j < 8; ++j) {
                a[j] += xn.x * w[j] + xn.y * w[64 + j] + xn.z * w[128 + j] + xn.w * w[192 + j];
                int col = flane * 8 + j;
                float s = gamma[col] * rsqrtf(rvar[col] + BN_EPS);
                v[j] = (a[j] + b0[col] - rmean[col]) * s + beta[col];
            }
            ushort4 p0, p1;
            p0.x = f2bf(v[0]); p0.y = f2bf(v[1]); p0.z = f2bf(v[2]); p0.w = f2bf(v[3]);
            p1.x = f2bf(v[4]); p1.y = f2bf(v[5]); p1.z = f2bf(v[6]); p1.w = f2bf(v[7]);
            *(ushort4*)&outb[(size_t)n * 64 + flane * 8]     = p0;
            *(ushort4*)&outb[(size_t)n * 64 + flane * 8 + 4] = p1;
        }
    }
}

// ---------------- hidden transform: one (64-node tile, relation) per block ----------
// T[r][n][:] = h[n][:] @ W_item(c0+r); LDS-staged D for coalesced dwordx4 T writes.
__global__ __launch_bounds__(256) void xform_kernel(
    const unsigned short* __restrict__ hin, const unsigned short* __restrict__ WtL,
    unsigned short* __restrict__ T, int c0) {
    __shared__ unsigned short tile[64 * 72];
    const int tid  = threadIdx.x;
    const int n0   = blockIdx.x * 64;
    const int r    = blockIdx.y;
    const int wv   = tid >> 6;
    const int lane = tid & 63;
    const int frow = lane & 15;
    const int kgrp = lane >> 4;
    int arc = min(n0 + wv * 16 + frow, NN - 1);
    bf16x8 a0 = *(const bf16x8*)&hin[(size_t)arc * 64 + kgrp * 8];
    bf16x8 a1 = *(const bf16x8*)&hin[(size_t)arc * 64 + 32 + kgrp * 8];
    const unsigned short* Wr = WtL + (size_t)(c0 + r) * 4096;
    unsigned short* Tr = T + (size_t)r * NN * 64;
    #pragma unroll
    for (int cf = 0; cf < 4; ++cf) {
        bf16x8 b0 = *(const bf16x8*)&Wr[(cf * 16 + frow) * 64 + kgrp * 8];
        bf16x8 b1 = *(const bf16x8*)&Wr[(cf * 16 + frow) * 64 + 32 + kgrp * 8];
        f32x4 d = {0.f, 0.f, 0.f, 0.f};
        d = __builtin_amdgcn_mfma_f32_16x16x32_bf16(a0, b0, d, 0, 0, 0);
        d = __builtin_amdgcn_mfma_f32_16x16x32_bf16(a1, b1, d, 0, 0, 0);
        #pragma unroll
        for (int j = 0; j < 4; ++j)
            tile[(wv * 16 + kgrp * 4 + j) * 72 + cf * 16 + frow] = f2bf(d[j]);
    }
    __syncthreads();
    #pragma unroll
    for (int i = tid; i < 512; i += 256) {
        int row = i >> 3, c16 = i & 7;
        int node = n0 + row;
        if (node < NN)
            *(uint4*)&Tr[(size_t)node * 64 + c16 * 8] =
                *(const uint4*)&tile[row * 72 + c16 * 8];
    }
}

// ---------------- aggregate: out[n] = sum_e ic*T[rel][src] (+root, +accum, +BN) -----
template <bool FIRST, bool LASTP, bool LASTL>
__global__ __launch_bounds__(256) void agg_kernel(
    const unsigned short* __restrict__ T, const int* __restrict__ offs,
    const uint2* __restrict__ ep, float* __restrict__ accum, int c0, int c1,
    const float* __restrict__ bias, const float* __restrict__ gamma,
    const float* __restrict__ beta, const float* __restrict__ rmean,
    const float* __restrict__ rvar, unsigned short* __restrict__ outb,
    float* __restrict__ outf) {
    constexpr bool FULL = FIRST && LASTP;
    int wid   = (blockIdx.x * 256 + threadIdx.x) >> 6;
    int nw    = (gridDim.x * 256) >> 6;
    int lane  = threadIdx.x & 63;
    int eslot = lane >> 3;
    int flane = lane & 7;
    const unsigned ce = (c1 < RR) ? (unsigned)c1 : (unsigned)RR;

    for (int n = wid; n < NN; n += nw) {
        int e0 = offs[n], e1 = offs[n + 1];
        float a[8] = {0, 0, 0, 0, 0, 0, 0, 0};
        for (int e = e0 + eslot; e < e1; e += 8) {
            uint2 m = ep[e];
            unsigned r = m.x >> 20;
            if (FULL || (r >= (unsigned)c0 && r < ce)) {
                float ic = __uint_as_float(m.y);
                size_t ti = ((size_t)(r - c0) * NN + (m.x & 0xFFFFF)) * 64;
                uint4 row = *(const uint4*)&T[ti + flane * 8];
                float v[8]; unpack8(row, v);
                #pragma unroll
                for (int j = 0; j < 8; ++j) a[j] += ic * v[j];
            }
        }
        #pragma unroll
        for (int off = 8; off < 64; off <<= 1)
            #pragma unroll
            for (int j = 0; j < 8; ++j) a[j] += __shfl_xor(a[j], off);

        if (eslot == 0) {
            if (LASTP) {
                uint4 rr = *(const uint4*)&T[((size_t)(20 - c0) * NN + n) * 64 + flane * 8];
                float rv[8]; unpack8(rr, rv);
                #pragma unroll
                for (int j = 0; j < 8; ++j) a[j] += rv[j];
            }
            if (!FIRST) {
                float4 p0 = *(const float4*)&accum[(size_t)n * 64 + flane * 8];
                float4 p1 = *(const float4*)&accum[(size_t)n * 64 + flane * 8 + 4];
                a[0] += p0.x; a[1] += p0.y; a[2] += p0.z; a[3] += p0.w;
                a[4] += p1.x; a[5] += p1.y; a[6] += p1.z; a[7] += p1.w;
            }
            if (!LASTP) {
                *(float4*)&accum[(size_t)n * 64 + flane * 8] =
                    make_float4(a[0], a[1], a[2], a[3]);
                *(float4*)&accum[(size_t)n * 64 + flane * 8 + 4] =
                    make_float4(a[4], a[5], a[6], a[7]);
            } else {
                float v[8];
                #pragma unroll
                for (int j = 0; j < 8; ++j) {
                    int col = flane * 8 + j;
                    float s = gamma[col] * rsqrtf(rvar[col] + BN_EPS);
                    v[j] = (a[j] + bias[col] - rmean[col]) * s + beta[col];
                }
                if (LASTL) {
                    float4 o0 = make_float4(fmaxf(v[0],0.f), fmaxf(v[1],0.f),
                                            fmaxf(v[2],0.f), fmaxf(v[3],0.f));
                    float4 o1 = make_float4(fmaxf(v[4],0.f), fmaxf(v[5],0.f),
                                            fmaxf(v[6],0.f), fmaxf(v[7],0.f));
                    *(float4*)&outf[(size_t)n * 64 + flane * 8]     = o0;
                    *(float4*)&outf[(size_t)n * 64 + flane * 8 + 4] = o1;
                } else {
                    ushort4 p0, p1;
                    p0.x = f2bf(v[0]); p0.y = f2bf(v[1]);
                    p0.z = f2bf(v[2]); p0.w = f2bf(v[3]);
                    p1.x = f2bf(v[4]); p1.y = f2bf(v[5]);
                    p1.z = f2bf(v[6]); p1.w = f2bf(v[7]);
                    *(ushort4*)&outb[(size_t)n * 64 + flane * 8]     = p0;
                    *(ushort4*)&outb[(size_t)n * 64 + flane * 8 + 4] = p1;
                }
            }
        }
    }
}

extern "C" void kernel_launch(void* const* d_in, const int* in_sizes, int n_in,
                              void* d_out, int out_size, void* d_ws, size_t ws_size,
                              hipStream_t stream) {
    const float* x     = (const float*)d_in[0];
    const int*   ei    = (const int*)d_in[1];
    const int*   et    = (const int*)d_in[2];
    const float* W0    = (const float*)d_in[3];
    const float* root0 = (const float*)d_in[4];
    const float* b0    = (const float*)d_in[5];
    const float* Wh    = (const float*)d_in[6];
    const float* rooth = (const float*)d_in[7];
    const float* bh    = (const float*)d_in[8];
    const float* gamma = (const float*)d_in[9];
    const float* beta  = (const float*)d_in[10];
    const float* rmean = (const float*)d_in[11];
    const float* rvar  = (const float*)d_in[12];
    float* out = (float*)d_out;

    const int* src = ei;
    const int* dst = ei + NE;

    // workspace layout (fixed ≈ 30 MB, then T chunk up to 134.4 MB)
    int*   cntdr = (int*)d_ws;                        // 1,000,000
    int*   deg   = cntdr + 1000000;                   // 50,000
    int*   fill  = deg + 50000;                       // 50,000
    int*   offs  = fill + 50000;                      // 50,004
    int*   bsums = offs + 50004;                      // 1,024
    uint2* ep    = (uint2*)(bsums + 1024);            // NE x 8B
    unsigned short* Wt = (unsigned short*)(ep + NE);  // 3*21*4096
    unsigned short* h0 = Wt + 3 * 21 * 4096;          // N*64
    unsigned short* h1 = h0 + NN * 64;                // N*64
    float* accum = (float*)(h1 + NN * 64);            // N*64 fp32
    unsigned short* T = (unsigned short*)(accum + NN * 64);

    size_t used  = (size_t)((char*)T - (char*)d_ws);
    size_t avail = (ws_size > used) ? ws_size - used : 0;
    size_t per   = (size_t)NN * 64 * 2;
    int nrel = (int)(avail / per);
    if (nrel < 1) nrel = 1;
    if (nrel > 21) nrel = 21;
    int npass = (21 + nrel - 1) / nrel;

    // ---- CSR build: dst-grouped edges + (dst,rel) histogram for inv_cnt ----
    hipMemsetAsync(cntdr, 0, (size_t)NN * RR * sizeof(int), stream);
    hipMemsetAsync(fill, 0, (size_t)NN * sizeof(int), stream);
    count_kernel<<<2048, 256, 0, stream>>>(dst, et, cntdr);
    deg_kernel<<<256, 256, 0, stream>>>(cntdr, deg);
    scan1_kernel<<<SCAN_NB, 256, 0, stream>>>(deg, offs, bsums, NN);
    scan_top_kernel<<<1, 1024, 0, stream>>>(bsums, SCAN_NB);
    scan_add_kernel<<<256, 256, 0, stream>>>(offs, bsums, NN);
    fill_kernel<<<2048, 256, 0, stream>>>(src, dst, et, offs, cntdr, fill, ep);
    wprep_kernel<<<63, 256, 0, stream>>>(Wh, rooth, Wt);

    // ---- layer 0: fully fused ----
    agg0_kernel<<<2048, 256, 0, stream>>>(
        x, offs, ep, W0, root0, b0, gamma, beta, rmean, rvar, h0);

    // ---- layers 1..3: chunked (tile, rel)-parallel transform + aggregate ----
    const int XB = (NN + 63) / 64;   // 782
    for (int l = 1; l < 4; ++l) {
        const unsigned short* hin = (l == 2) ? h1 : h0;
        unsigned short* hout = (l == 1) ? h1 : h0;
        const float* bl  = bh + (size_t)(l - 1) * 64;
        const float* gl  = gamma + (size_t)l * 64;
        const float* btl = beta + (size_t)l * 64;
        const float* rml = rmean + (size_t)l * 64;
        const float* rvl = rvar + (size_t)l * 64;
        int c0 = 0;
        for (int p = 0; p < npass; ++p) {
            int c1 = c0 + nrel; if (c1 > 21) c1 = 21;
            dim3 xg(XB, c1 - c0);
            xform_kernel<<<xg, 256, 0, stream>>>(
                hin, Wt + (size_t)(l - 1) * 21 * 4096, T, c0);
            bool first = (p == 0), lastp = (p == npass - 1);
            bool lastl = lastp && (l == 3);
            #define AGG(F, LP, LL) agg_kernel<F, LP, LL><<<2048, 256, 0, stream>>>( \
                T, offs, ep, accum, c0, c1, bl, gl, btl, rml, rvl, hout, out)
            if (first && lastp && lastl)      AGG(true,  true,  true);
            else if (first && lastp)          AGG(true,  true,  false);
            else if (first)                   AGG(true,  false, false);
            else if (lastp && lastl)          AGG(false, true,  true);
            else if (lastp)                   AGG(false, true,  false);
            else                              AGG(false, false, false);
            #undef AGG
            c0 = c1;
        }
    }
}